// Round 3
// baseline (699.637 us; speedup 1.0000x reference)
//
#include <hip/hip_runtime.h>

#define NF 481
#define NT 500
#define CH 16
#define HID 32
#define NB 16
#define NSEQ (NB*NF)   // 7696

typedef __attribute__((ext_vector_type(8))) short short8;
typedef __attribute__((ext_vector_type(4))) float f32x4;

// fast sigmoid — v_rcp instead of correctly-rounded divide (R10 win)
__device__ __forceinline__ float sig_(float v) {
    return __builtin_amdgcn_rcpf(1.0f + __expf(-v));
}

__device__ __forceinline__ unsigned short f2bf(float f) {
    unsigned u = __float_as_uint(f);
    u = (u + 0x7fffu + ((u >> 16) & 1u)) >> 16;   // RNE
    return (unsigned short)u;
}
__device__ __forceinline__ unsigned int pk2(float a, float b) {
    return (unsigned int)f2bf(a) | ((unsigned int)f2bf(b) << 16);
}
__device__ __forceinline__ float bf2f(short s) {
    return __uint_as_float(((unsigned)(unsigned short)s) << 16);
}

// -------------------------------------------------------------------------
// Fused conv1(4->16,k9,p4)+PReLU -> LDS bf16 -> conv2(16->16,k5,p2) via MFMA
// (hi/lo bf16 weight split preserves fp32-weight numerics) + PReLU -> x.
// Block: 4 waves, 4 output f, 128 t.  Kills the 123MB y1 HBM round-trip and
// conv2's 5120-fma/thread VALU cost.  LDS row stride 24 ch: 16B-aligned
// b128s, read conflicts at the free 2-way level.
// -------------------------------------------------------------------------
__global__ __launch_bounds__(256) void conv_fused_kernel(
    const float* __restrict__ feat,
    const float* __restrict__ w1, const float* __restrict__ b1, const float* __restrict__ a1p,
    const float* __restrict__ w2, const float* __restrict__ b2, const float* __restrict__ a2p,
    unsigned short* __restrict__ xout)
{
    __shared__ unsigned short ylds[8*128*24];    // 48 KB: [row8][t128][ch16+pad8]
    const int b    = blockIdx.x;
    const int f0   = blockIdx.y * 4;
    const int tg   = blockIdx.z * 128;
    const int wid  = threadIdx.x >> 6;
    const int lane = threadIdx.x & 63;
    const float al1 = a1p[0];

    // ---- phase 1: conv1 (exact fp32) for rows f0-2 .. f0+5; wave w -> rows 2w,2w+1
    const int tl0 = lane*2;                      // local t pair (0..126)
    const int bc  = (tg + tl0 <= NT-2) ? (tg + tl0) : (NT-2);   // clamped even global t
    #pragma unroll
    for (int rr = 0; rr < 2; rr++) {
        const int rloc = wid*2 + rr;
        const int fr   = f0 - 2 + rloc;
        unsigned short* yw = &ylds[(rloc*128 + tl0)*24];
        if (fr >= 0 && fr < NF) {
            float2 q[16];
            #pragma unroll
            for (int ch = 0; ch < 16; ch++) { q[ch].x = b1[ch]; q[ch].y = b1[ch]; }
            #pragma unroll
            for (int k = 0; k < 9; k++) {
                const int gf = fr + k - 4;
                if (gf >= 0 && gf < NF) {
                    #pragma unroll
                    for (int d = 0; d < 4; d++) {
                        const float2 v = *(const float2*)(feat +
                            ((size_t)(b*4 + d)*NF + gf)*NT + bc);
                        #pragma unroll
                        for (int ch = 0; ch < 16; ch++) {
                            const float w = w1[ch*36 + d*9 + k];
                            q[ch].x = fmaf(w, v.x, q[ch].x);
                            q[ch].y = fmaf(w, v.y, q[ch].y);
                        }
                    }
                }
            }
            unsigned px[8], py[8];
            #pragma unroll
            for (int i = 0; i < 8; i++) {
                float ax = q[2*i].x,  bx = q[2*i+1].x;
                float ay = q[2*i].y,  by = q[2*i+1].y;
                ax = (ax >= 0.f) ? ax : al1*ax;  bx = (bx >= 0.f) ? bx : al1*bx;
                ay = (ay >= 0.f) ? ay : al1*ay;  by = (by >= 0.f) ? by : al1*by;
                px[i] = pk2(ax, bx);  py[i] = pk2(ay, by);
            }
            *(uint4*)(yw)          = make_uint4(px[0],px[1],px[2],px[3]);
            *(uint4*)(yw + 8)      = make_uint4(px[4],px[5],px[6],px[7]);
            *(uint4*)(yw + 24)     = make_uint4(py[0],py[1],py[2],py[3]);
            *(uint4*)(yw + 24 + 8) = make_uint4(py[4],py[5],py[6],py[7]);
        } else {
            *(uint4*)(yw)          = make_uint4(0,0,0,0);
            *(uint4*)(yw + 8)      = make_uint4(0,0,0,0);
            *(uint4*)(yw + 24)     = make_uint4(0,0,0,0);
            *(uint4*)(yw + 24 + 8) = make_uint4(0,0,0,0);
        }
    }
    __syncthreads();

    // ---- phase 2: conv2 via MFMA.  wave w -> output f = f0+w.
    // k = kk*16 + ci (K=96, kk=5 zero).  A row = t (lane&15), B col = cout.
    const int c    = lane & 15;
    const int quad = lane >> 4;
    const int f    = f0 + wid;
    if (f < NF) {
        const float al2 = a2p[0];
        short8 Bh0, Bh1, Bh2, Bl0, Bl1, Bl2;
        #define MKB2(BH, BL, Q)                                                \
            { _Pragma("unroll") for (int j = 0; j < 8; j++) {                  \
                const int ci = (quad & 1)*8 + j;                               \
                const int kk = 2*(Q) + (quad >> 1);                            \
                float w = 0.f;                                                 \
                if (kk < 5) w = w2[c*80 + ci*5 + kk];                          \
                const unsigned short hb = f2bf(w);                             \
                const float hf = bf2f((short)hb);                              \
                BH[j] = (short)hb;                                             \
                BL[j] = (short)f2bf(w - hf); } }
        MKB2(Bh0, Bl0, 0); MKB2(Bh1, Bl1, 1); MKB2(Bh2, Bl2, 2);
        #undef MKB2

        const f32x4 cb = {b2[c], b2[c], b2[c], b2[c]};
        const int ci0 = (quad & 1)*8;
        const int r0  = wid + (quad >> 1);       // A row base: wid + kk, kk = 2q+(quad>>1)
        unsigned short* xo = xout + ((size_t)(b*NF + f)*NT)*CH + c;

        #pragma unroll
        for (int ti = 0; ti < 8; ti++) {
            const int t = ti*16 + c;             // A row (t within wave's 128-slice)
            const int rl2 = (r0 + 4 > 7) ? 7 : (r0 + 4);   // kk=5 half clamps (B=0 there)
            const short8 a0 = *(const short8*)&ylds[((r0    )*128 + t)*24 + ci0];
            const short8 a1 = *(const short8*)&ylds[((r0 + 2)*128 + t)*24 + ci0];
            const short8 a2 = *(const short8*)&ylds[((rl2   )*128 + t)*24 + ci0];
            f32x4 acc = cb;
            acc = __builtin_amdgcn_mfma_f32_16x16x32_bf16(a0, Bl0, acc, 0, 0, 0);
            acc = __builtin_amdgcn_mfma_f32_16x16x32_bf16(a1, Bl1, acc, 0, 0, 0);
            acc = __builtin_amdgcn_mfma_f32_16x16x32_bf16(a2, Bl2, acc, 0, 0, 0);
            acc = __builtin_amdgcn_mfma_f32_16x16x32_bf16(a0, Bh0, acc, 0, 0, 0);
            acc = __builtin_amdgcn_mfma_f32_16x16x32_bf16(a1, Bh1, acc, 0, 0, 0);
            acc = __builtin_amdgcn_mfma_f32_16x16x32_bf16(a2, Bh2, acc, 0, 0, 0);
            // C layout: col = c = cout, row = quad*4 + r = t within tile
            #pragma unroll
            for (int r = 0; r < 4; r++) {
                const int tt = tg + ti*16 + quad*4 + r;
                if (tt < NT) {
                    float v = acc[r];
                    v = (v >= 0.f) ? v : al2*v;
                    xo[(size_t)tt*CH] = f2bf(v);
                }
            }
        }
    }
}

// -------------------------------------------------------------------------
// GRU via MFMA — R10 single-wave structure (proven 352 us).  R11's 4-wave
// split regressed (barrier-per-step + duplicated critical path + 2.5x LDS
// conflicts); reverted verbatim.
// -------------------------------------------------------------------------
__global__ __launch_bounds__(64) void gru_kernel(
    const unsigned short* __restrict__ xin,  // (NSEQ, NT, 16) bf16
    const float* __restrict__ h0,    // (NSEQ, 32)
    const float* __restrict__ w_ih,  // (96, 16)
    const float* __restrict__ w_hh,  // (96, 32)
    const float* __restrict__ b_ih, const float* __restrict__ b_hh,
    const float* __restrict__ fc_w, const float* __restrict__ fc_b,
    float* __restrict__ prob,        // (NSEQ, NT)
    float* __restrict__ hout)        // (NSEQ, 32)
{
    __shared__ unsigned short sv[16*72];     // [seq][x16|h32|pad16] bf16
    const int lane = threadIdx.x & 63;
    const int c    = lane & 15;
    const int quad = lane >> 4;
    const int base = blockIdx.x * 16;        // 481 blocks x 16 seq

    #define MKB(DST, G, CK)                                                    \
        { _Pragma("unroll") for (int j = 0; j < 8; j++) {                      \
            const int k = (CK)*32 + quad*8 + j;                                \
            const int g = (G);                                                 \
            float wv_;                                                         \
            if (g < 64)      wv_ = (k < 16) ? w_ih[g*16 + k]                   \
                                  : (k < 48) ? w_hh[g*32 + k - 16] : 0.f;      \
            else if (g < 96) wv_ = (k < 16) ? w_ih[g*16 + k] : 0.f;            \
            else             wv_ = (k >= 16 && k < 48)                         \
                                  ? w_hh[(g-32)*32 + k - 16] : 0.f;            \
            DST[j] = (short)f2bf(wv_); } }

    short8 B0a, B0b, B1a, B1b, B2a, B2b, B3a, B3b, B4a, B5a, B6a, B6b, B7a, B7b;
    MKB(B0a,       c, 0); MKB(B0b,       c, 1);   // r  units 0..15
    MKB(B1a,  16 + c, 0); MKB(B1b,  16 + c, 1);   // r  units 16..31
    MKB(B2a,  32 + c, 0); MKB(B2b,  32 + c, 1);   // z
    MKB(B3a,  48 + c, 0); MKB(B3b,  48 + c, 1);
    MKB(B4a,  64 + c, 0);                          // xn (chunk1 all-zero)
    MKB(B5a,  80 + c, 0);
    MKB(B6a,  96 + c, 0); MKB(B6b,  96 + c, 1);   // hn
    MKB(B7a, 112 + c, 0); MKB(B7b, 112 + c, 1);

    const float bi0 = b_ih[c]      + b_hh[c];
    const float bi1 = b_ih[16 + c] + b_hh[16 + c];
    const float bi2 = b_ih[32 + c] + b_hh[32 + c];
    const float bi3 = b_ih[48 + c] + b_hh[48 + c];
    const float bi4 = b_ih[64 + c];
    const float bi5 = b_ih[80 + c];
    const float bi6 = b_hh[64 + c];
    const float bi7 = b_hh[80 + c];
    const float fb = fc_b[0];

    // loop-invariant bias vectors fed straight into the first MFMA as C
    const f32x4 cb0 = {bi0, bi0, bi0, bi0};
    const f32x4 cb1 = {bi1, bi1, bi1, bi1};
    const f32x4 cb2 = {bi2, bi2, bi2, bi2};
    const f32x4 cb3 = {bi3, bi3, bi3, bi3};
    const f32x4 cb4 = {bi4, bi4, bi4, bi4};
    const f32x4 cb5 = {bi5, bi5, bi5, bi5};
    const f32x4 cb6 = {bi6, bi6, bi6, bi6};
    const f32x4 cb7 = {bi7, bi7, bi7, bi7};

    // per-lane FC slice: this lane reads h units u0..u0+7 of seq c
    const int u0 = (quad == 0) ? 16 : (quad == 1) ? 24 : (quad == 2) ? 0 : 8;
    float fsl0 = fc_w[u0+0], fsl1 = fc_w[u0+1], fsl2 = fc_w[u0+2], fsl3 = fc_w[u0+3];
    float fsl4 = fc_w[u0+4], fsl5 = fc_w[u0+5], fsl6 = fc_w[u0+6], fsl7 = fc_w[u0+7];

    float hp00 = h0[(size_t)(base + quad*4 + 0)*HID + c];
    float hp01 = h0[(size_t)(base + quad*4 + 0)*HID + 16 + c];
    float hp10 = h0[(size_t)(base + quad*4 + 1)*HID + c];
    float hp11 = h0[(size_t)(base + quad*4 + 1)*HID + 16 + c];
    float hp20 = h0[(size_t)(base + quad*4 + 2)*HID + c];
    float hp21 = h0[(size_t)(base + quad*4 + 2)*HID + 16 + c];
    float hp30 = h0[(size_t)(base + quad*4 + 3)*HID + c];
    float hp31 = h0[(size_t)(base + quad*4 + 3)*HID + 16 + c];

    // ---- init LDS v-buffer ----
    *(uint2*)&sv[(lane >> 2)*72 + 48 + (lane & 3)*4] = make_uint2(0u, 0u);
    sv[(quad*4 + 0)*72 + 16 + c] = f2bf(hp00);  sv[(quad*4 + 0)*72 + 32 + c] = f2bf(hp01);
    sv[(quad*4 + 1)*72 + 16 + c] = f2bf(hp10);  sv[(quad*4 + 1)*72 + 32 + c] = f2bf(hp11);
    sv[(quad*4 + 2)*72 + 16 + c] = f2bf(hp20);  sv[(quad*4 + 2)*72 + 32 + c] = f2bf(hp21);
    sv[(quad*4 + 3)*72 + 16 + c] = f2bf(hp30);  sv[(quad*4 + 3)*72 + 32 + c] = f2bf(hp31);
    const unsigned short* xrow = xin + ((size_t)(base + (lane >> 2)))*NT*CH + (lane & 3)*4;
    {
        const uint2 x0v = *(const uint2*)(xrow);
        *(uint2*)&sv[(lane >> 2)*72 + (lane & 3)*4] = x0v;
    }
    uint2 nxA = *(const uint2*)(xrow + 1*CH);   // x(t=1)
    uint2 nxB = *(const uint2*)(xrow + 2*CH);   // x(t=2)
    __builtin_amdgcn_wave_barrier();

    #define GSTEP(R, HP0, HP1)                                                 \
        {                                                                      \
            const float rr0 = sig_(acc0[R]);                                   \
            const float rr1 = sig_(acc1[R]);                                   \
            const float zz0 = sig_(acc2[R]);                                   \
            const float zz1 = sig_(acc3[R]);                                   \
            const float aa0 = fmaf(rr0, acc6[R], acc4[R]);                     \
            const float aa1 = fmaf(rr1, acc7[R], acc5[R]);                     \
            const float nn0 = fmaf(2.f, sig_(2.f*aa0), -1.f);                  \
            const float nn1 = fmaf(2.f, sig_(2.f*aa1), -1.f);                  \
            HP0 = fmaf(zz0, HP0 - nn0, nn0);                                   \
            HP1 = fmaf(zz1, HP1 - nn1, nn1);                                   \
            unsigned hpk_;                                                     \
            asm("v_cvt_pk_bf16_f32 %0, %1, %2"                                 \
                : "=v"(hpk_) : "v"(HP0), "v"(HP1));                            \
            sv[(quad*4 + (R))*72 + 16 + c] = (unsigned short)hpk_;             \
            sv[(quad*4 + (R))*72 + 32 + c] = (unsigned short)(hpk_ >> 16);     \
        }

    for (int t = 0; t < NT; t++) {
        const short8 a0  = *(const short8*)&sv[c*72 + quad*8];        // k 0..31
        const short8 a1  = *(const short8*)&sv[c*72 + 32 + quad*8];   // k 32..63
        const short8 hs8 = *(const short8*)&sv[c*72 + 16 + u0];       // h slice
        __builtin_amdgcn_wave_barrier();   // pin reads before this iter's writes

        // FC partial for prob[t-1] (h_t is in sv): 8-term dot
        float pa;
        pa = bf2f(hs8[0])*fsl0;
        pa = fmaf(bf2f(hs8[1]), fsl1, pa);
        pa = fmaf(bf2f(hs8[2]), fsl2, pa);
        pa = fmaf(bf2f(hs8[3]), fsl3, pa);
        pa = fmaf(bf2f(hs8[4]), fsl4, pa);
        pa = fmaf(bf2f(hs8[5]), fsl5, pa);
        pa = fmaf(bf2f(hs8[6]), fsl6, pa);
        pa = fmaf(bf2f(hs8[7]), fsl7, pa);
        pa += __shfl_xor(pa, 16);          // combine quad pairs (latency hidden by MFMAs)

        // prefetch x(t+3)
        const int tn = (t + 3 < NT) ? t + 3 : NT - 1;
        const uint2 fx = *(const uint2*)(xrow + (size_t)tn*CH);

        f32x4 acc0 = __builtin_amdgcn_mfma_f32_16x16x32_bf16(a0, B0a, cb0, 0, 0, 0);
        f32x4 acc1 = __builtin_amdgcn_mfma_f32_16x16x32_bf16(a0, B1a, cb1, 0, 0, 0);
        f32x4 acc2 = __builtin_amdgcn_mfma_f32_16x16x32_bf16(a0, B2a, cb2, 0, 0, 0);
        f32x4 acc3 = __builtin_amdgcn_mfma_f32_16x16x32_bf16(a0, B3a, cb3, 0, 0, 0);
        f32x4 acc4 = __builtin_amdgcn_mfma_f32_16x16x32_bf16(a0, B4a, cb4, 0, 0, 0);
        f32x4 acc5 = __builtin_amdgcn_mfma_f32_16x16x32_bf16(a0, B5a, cb5, 0, 0, 0);
        f32x4 acc6 = __builtin_amdgcn_mfma_f32_16x16x32_bf16(a0, B6a, cb6, 0, 0, 0);
        f32x4 acc7 = __builtin_amdgcn_mfma_f32_16x16x32_bf16(a0, B7a, cb7, 0, 0, 0);
        acc0 = __builtin_amdgcn_mfma_f32_16x16x32_bf16(a1, B0b, acc0, 0, 0, 0);
        acc1 = __builtin_amdgcn_mfma_f32_16x16x32_bf16(a1, B1b, acc1, 0, 0, 0);
        acc2 = __builtin_amdgcn_mfma_f32_16x16x32_bf16(a1, B2b, acc2, 0, 0, 0);
        acc3 = __builtin_amdgcn_mfma_f32_16x16x32_bf16(a1, B3b, acc3, 0, 0, 0);
        acc6 = __builtin_amdgcn_mfma_f32_16x16x32_bf16(a1, B6b, acc6, 0, 0, 0);
        acc7 = __builtin_amdgcn_mfma_f32_16x16x32_bf16(a1, B7b, acc7, 0, 0, 0);

        // finish the FC reduction + store (prob for step t-1)
        pa += __shfl_xor(pa, 32);
        if (t > 0 && lane < 16)
            prob[(size_t)(base + c)*NT + (t - 1)] = sig_(pa + fb);

        GSTEP(0, hp00, hp01);
        GSTEP(1, hp10, hp11);
        GSTEP(2, hp20, hp21);
        GSTEP(3, hp30, hp31);

        // stage x(t+1), rotate prefetch pipeline
        *(uint2*)&sv[(lane >> 2)*72 + (lane & 3)*4] = nxA;
        nxA = nxB; nxB = fx;
        __builtin_amdgcn_wave_barrier();
    }

    // prob for the final step (h_NT is in sv)
    {
        const short8 hs8 = *(const short8*)&sv[c*72 + 16 + u0];
        float pa;
        pa = bf2f(hs8[0])*fsl0;
        pa = fmaf(bf2f(hs8[1]), fsl1, pa);
        pa = fmaf(bf2f(hs8[2]), fsl2, pa);
        pa = fmaf(bf2f(hs8[3]), fsl3, pa);
        pa = fmaf(bf2f(hs8[4]), fsl4, pa);
        pa = fmaf(bf2f(hs8[5]), fsl5, pa);
        pa = fmaf(bf2f(hs8[6]), fsl6, pa);
        pa = fmaf(bf2f(hs8[7]), fsl7, pa);
        pa += __shfl_xor(pa, 16);
        pa += __shfl_xor(pa, 32);
        if (lane < 16)
            prob[(size_t)(base + c)*NT + (NT - 1)] = sig_(pa + fb);
    }

    hout[(size_t)(base + quad*4 + 0)*HID + c]      = hp00;
    hout[(size_t)(base + quad*4 + 0)*HID + 16 + c] = hp01;
    hout[(size_t)(base + quad*4 + 1)*HID + c]      = hp10;
    hout[(size_t)(base + quad*4 + 1)*HID + 16 + c] = hp11;
    hout[(size_t)(base + quad*4 + 2)*HID + c]      = hp20;
    hout[(size_t)(base + quad*4 + 2)*HID + 16 + c] = hp21;
    hout[(size_t)(base + quad*4 + 3)*HID + c]      = hp30;
    hout[(size_t)(base + quad*4 + 3)*HID + 16 + c] = hp31;
}

// -------------------------------------------------------------------------
extern "C" void kernel_launch(void* const* d_in, const int* in_sizes, int n_in,
                              void* d_out, int out_size, void* d_ws, size_t ws_size,
                              hipStream_t stream)
{
    const float* feat = (const float*)d_in[0];
    const float* h0   = (const float*)d_in[1];
    const float* w1   = (const float*)d_in[2];
    const float* b1   = (const float*)d_in[3];
    const float* a1   = (const float*)d_in[4];
    const float* w2   = (const float*)d_in[5];
    const float* b2   = (const float*)d_in[6];
    const float* a2   = (const float*)d_in[7];
    const float* wih  = (const float*)d_in[8];
    const float* whh  = (const float*)d_in[9];
    const float* bih  = (const float*)d_in[10];
    const float* bhh  = (const float*)d_in[11];
    const float* fcw  = (const float*)d_in[12];
    const float* fcb  = (const float*)d_in[13];

    unsigned short* xbuf = (unsigned short*)d_ws;            // 123.1 MB bf16
    float* prob = (float*)d_out;                             // (B, F, T)
    float* hout = prob + (size_t)NSEQ*NT;                    // (1, NSEQ, 32)

    dim3 cgrid(NB, 121, 4);                                  // 4 f x 128 t per block
    conv_fused_kernel<<<cgrid, 256, 0, stream>>>(feat, w1, b1, a1, w2, b2, a2, xbuf);
    gru_kernel<<<NSEQ/16, 64, 0, stream>>>(xbuf, h0, wih, whh, bih, bhh, fcw, fcb, prob, hout);
}

// Round 5
// 652.019 us; speedup vs baseline: 1.0730x; 1.0730x over previous
//
#include <hip/hip_runtime.h>

#define NF 481
#define NT 500
#define CH 16
#define HID 32
#define NB 16
#define NSEQ (NB*NF)   // 7696

typedef __attribute__((ext_vector_type(8))) short short8;
typedef __attribute__((ext_vector_type(4))) float f32x4;

// fast sigmoid — v_rcp instead of correctly-rounded divide (R10 win)
__device__ __forceinline__ float sig_(float v) {
    return __builtin_amdgcn_rcpf(1.0f + __expf(-v));
}

__device__ __forceinline__ unsigned short f2bf(float f) {
    unsigned u = __float_as_uint(f);
    u = (u + 0x7fffu + ((u >> 16) & 1u)) >> 16;   // RNE
    return (unsigned short)u;
}
__device__ __forceinline__ unsigned int pk2(float a, float b) {
    return (unsigned int)f2bf(a) | ((unsigned int)f2bf(b) << 16);
}
__device__ __forceinline__ float bf2f(short s) {
    return __uint_as_float(((unsigned)(unsigned short)s) << 16);
}
__device__ __forceinline__ float4 prelu4(float4 v, float a) {
    v.x = (v.x >= 0.f) ? v.x : a*v.x;
    v.y = (v.y >= 0.f) ? v.y : a*v.y;
    v.z = (v.z >= 0.f) ? v.z : a*v.z;
    v.w = (v.w >= 0.f) ? v.w : a*v.w;
    return v;
}

#define FMA4(Q, W, V)                     \
    Q.x = fmaf((W), (V).x, Q.x);          \
    Q.y = fmaf((W), (V).y, Q.y);          \
    Q.z = fmaf((W), (V).z, Q.z);          \
    Q.w = fmaf((W), (V).w, Q.w)

// -------------------------------------------------------------------------
// Pass 1: conv1(4->16,k9,p4) + PReLU.  Compute identical to the proven
// 160us kernel (no duplication, issue-bound); store layout (b, f, t, ch)
// so conv2's MFMA A-fragments are contiguous.  128B-contiguous per lane.
// -------------------------------------------------------------------------
#define P1TAP(D, K1)                                                           \
    {                                                                          \
        const int gf = f + (K1) - 4;                                           \
        if (gf >= 0 && gf < NF) {                                              \
            const float4 v = *(const float4*)(feat +                           \
                ((size_t)(b*4 + (D))*NF + gf)*NT + tc0);                       \
            FMA4(q0,  w1[ 0*36 + (D)*9 + (K1)], v);                            \
            FMA4(q1,  w1[ 1*36 + (D)*9 + (K1)], v);                            \
            FMA4(q2,  w1[ 2*36 + (D)*9 + (K1)], v);                            \
            FMA4(q3,  w1[ 3*36 + (D)*9 + (K1)], v);                            \
            FMA4(q4,  w1[ 4*36 + (D)*9 + (K1)], v);                            \
            FMA4(q5,  w1[ 5*36 + (D)*9 + (K1)], v);                            \
            FMA4(q6,  w1[ 6*36 + (D)*9 + (K1)], v);                            \
            FMA4(q7,  w1[ 7*36 + (D)*9 + (K1)], v);                            \
            FMA4(q8,  w1[ 8*36 + (D)*9 + (K1)], v);                            \
            FMA4(q9,  w1[ 9*36 + (D)*9 + (K1)], v);                            \
            FMA4(q10, w1[10*36 + (D)*9 + (K1)], v);                            \
            FMA4(q11, w1[11*36 + (D)*9 + (K1)], v);                            \
            FMA4(q12, w1[12*36 + (D)*9 + (K1)], v);                            \
            FMA4(q13, w1[13*36 + (D)*9 + (K1)], v);                            \
            FMA4(q14, w1[14*36 + (D)*9 + (K1)], v);                            \
            FMA4(q15, w1[15*36 + (D)*9 + (K1)], v);                            \
        }                                                                      \
    }

#define STX(OP, E, COMP)                                                       \
    *(uint4*)((OP) + (E)*CH) = make_uint4(                                     \
        pk2(q0.COMP, q1.COMP),  pk2(q2.COMP, q3.COMP),                         \
        pk2(q4.COMP, q5.COMP),  pk2(q6.COMP, q7.COMP));                        \
    *(uint4*)((OP) + (E)*CH + 8) = make_uint4(                                 \
        pk2(q8.COMP, q9.COMP),  pk2(q10.COMP, q11.COMP),                       \
        pk2(q12.COMP, q13.COMP), pk2(q14.COMP, q15.COMP))

__global__ __launch_bounds__(256) void conv1_kernel(
    const float* __restrict__ feat,
    const float* __restrict__ w1, const float* __restrict__ b1, const float* __restrict__ a1p,
    unsigned short* __restrict__ y1)          // (b, f, t, ch) bf16
{
    const int b    = blockIdx.x;
    const int wv   = threadIdx.x >> 6;
    const int lane = threadIdx.x & 63;
    const int f    = blockIdx.y*4 + wv;
    if (f >= NF) return;
    const int gt0  = blockIdx.z*256 + lane*4;
    const int tc0  = (gt0 <= NT-4) ? gt0 : (NT-4);
    const float al1 = a1p[0];

    float4 q0  = make_float4(b1[0],b1[0],b1[0],b1[0]);
    float4 q1  = make_float4(b1[1],b1[1],b1[1],b1[1]);
    float4 q2  = make_float4(b1[2],b1[2],b1[2],b1[2]);
    float4 q3  = make_float4(b1[3],b1[3],b1[3],b1[3]);
    float4 q4  = make_float4(b1[4],b1[4],b1[4],b1[4]);
    float4 q5  = make_float4(b1[5],b1[5],b1[5],b1[5]);
    float4 q6  = make_float4(b1[6],b1[6],b1[6],b1[6]);
    float4 q7  = make_float4(b1[7],b1[7],b1[7],b1[7]);
    float4 q8  = make_float4(b1[8],b1[8],b1[8],b1[8]);
    float4 q9  = make_float4(b1[9],b1[9],b1[9],b1[9]);
    float4 q10 = make_float4(b1[10],b1[10],b1[10],b1[10]);
    float4 q11 = make_float4(b1[11],b1[11],b1[11],b1[11]);
    float4 q12 = make_float4(b1[12],b1[12],b1[12],b1[12]);
    float4 q13 = make_float4(b1[13],b1[13],b1[13],b1[13]);
    float4 q14 = make_float4(b1[14],b1[14],b1[14],b1[14]);
    float4 q15 = make_float4(b1[15],b1[15],b1[15],b1[15]);

    #pragma unroll
    for (int d = 0; d < 4; d++) {
        P1TAP(d, 0); P1TAP(d, 1); P1TAP(d, 2); P1TAP(d, 3); P1TAP(d, 4);
        P1TAP(d, 5); P1TAP(d, 6); P1TAP(d, 7); P1TAP(d, 8);
    }

    if (gt0 < NT) {
        q0  = prelu4(q0,  al1); q1  = prelu4(q1,  al1);
        q2  = prelu4(q2,  al1); q3  = prelu4(q3,  al1);
        q4  = prelu4(q4,  al1); q5  = prelu4(q5,  al1);
        q6  = prelu4(q6,  al1); q7  = prelu4(q7,  al1);
        q8  = prelu4(q8,  al1); q9  = prelu4(q9,  al1);
        q10 = prelu4(q10, al1); q11 = prelu4(q11, al1);
        q12 = prelu4(q12, al1); q13 = prelu4(q13, al1);
        q14 = prelu4(q14, al1); q15 = prelu4(q15, al1);
        unsigned short* op = y1 + ((size_t)(b*NF + f)*NT + gt0)*CH;
        STX(op, 0, x); STX(op, 1, y); STX(op, 2, z); STX(op, 3, w);
    }
}

// -------------------------------------------------------------------------
// Pass 2: conv2(16->16,k5,p2) via MFMA (hi/lo bf16 weight split preserves
// fp32-weight numerics) + PReLU -> x (n,t,16) bf16.
// R5 FIX: staging loads/stores are uint4 (8 ushorts = one half-row of 8 ch).
// R4 used uint2 (4 ushorts) leaving ch 4-7/12-15 uninitialized -> NaN.
// -------------------------------------------------------------------------
__global__ __launch_bounds__(256) void conv2_kernel(
    const unsigned short* __restrict__ y1,    // (b, f, t, ch) bf16
    const float* __restrict__ w2, const float* __restrict__ b2, const float* __restrict__ a2p,
    unsigned short* __restrict__ xout)
{
    __shared__ unsigned short ylds[8*128*24];    // 48 KB: [row8][t128][ch16+pad8]
    const int b    = blockIdx.x;
    const int f0   = blockIdx.y * 4;
    const int tg   = blockIdx.z * 128;
    const int tid  = threadIdx.x;
    const int wid  = tid >> 6;
    const int lane = tid & 63;

    // ---- stage: rows f0-2 .. f0+5, zero-filled outside [0,NF) / [0,NT)
    #pragma unroll
    for (int i = 0; i < 8; i++) {
        const int idx  = tid + i*256;        // 0..2047
        const int row  = idx >> 8;           // 0..7
        const int tt   = (idx >> 1) & 127;
        const int half = idx & 1;
        const int fr   = f0 - 2 + row;
        const int gt   = tg + tt;
        uint4 v = make_uint4(0u, 0u, 0u, 0u);
        if (fr >= 0 && fr < NF && gt < NT)
            v = *(const uint4*)(y1 + ((size_t)(b*NF + fr)*NT + gt)*CH + half*8);
        *(uint4*)&ylds[(row*128 + tt)*24 + half*8] = v;
    }
    __syncthreads();

    // ---- conv2 via MFMA.  wave w -> output f = f0+w.
    const int c    = lane & 15;
    const int quad = lane >> 4;
    const int f    = f0 + wid;
    if (f < NF) {
        const float al2 = a2p[0];
        short8 Bh0, Bh1, Bh2, Bl0, Bl1, Bl2;
        #define MKB2(BH, BL, Q)                                                \
            { _Pragma("unroll") for (int j = 0; j < 8; j++) {                  \
                const int ci = (quad & 1)*8 + j;                               \
                const int kk = 2*(Q) + (quad >> 1);                            \
                float w = 0.f;                                                 \
                if (kk < 5) w = w2[c*80 + ci*5 + kk];                          \
                const unsigned short hb = f2bf(w);                             \
                const float hf = bf2f((short)hb);                              \
                BH[j] = (short)hb;                                             \
                BL[j] = (short)f2bf(w - hf); } }
        MKB2(Bh0, Bl0, 0); MKB2(Bh1, Bl1, 1); MKB2(Bh2, Bl2, 2);
        #undef MKB2

        const f32x4 cb = {b2[c], b2[c], b2[c], b2[c]};
        const int ci0 = (quad & 1)*8;
        const int r0  = wid + (quad >> 1);       // A row base: wid + kk, kk = 2q+(quad>>1)
        unsigned short* xo = xout + ((size_t)(b*NF + f)*NT)*CH + c;

        #pragma unroll
        for (int ti = 0; ti < 8; ti++) {
            const int t = ti*16 + c;             // A row (t within the 128-slice)
            const int rl2 = (r0 + 4 > 7) ? 7 : (r0 + 4);   // kk=5 half clamps (B=0 there)
            const short8 a0 = *(const short8*)&ylds[((r0    )*128 + t)*24 + ci0];
            const short8 a1 = *(const short8*)&ylds[((r0 + 2)*128 + t)*24 + ci0];
            const short8 a2 = *(const short8*)&ylds[((rl2   )*128 + t)*24 + ci0];
            f32x4 acc = cb;
            acc = __builtin_amdgcn_mfma_f32_16x16x32_bf16(a0, Bl0, acc, 0, 0, 0);
            acc = __builtin_amdgcn_mfma_f32_16x16x32_bf16(a1, Bl1, acc, 0, 0, 0);
            acc = __builtin_amdgcn_mfma_f32_16x16x32_bf16(a2, Bl2, acc, 0, 0, 0);
            acc = __builtin_amdgcn_mfma_f32_16x16x32_bf16(a0, Bh0, acc, 0, 0, 0);
            acc = __builtin_amdgcn_mfma_f32_16x16x32_bf16(a1, Bh1, acc, 0, 0, 0);
            acc = __builtin_amdgcn_mfma_f32_16x16x32_bf16(a2, Bh2, acc, 0, 0, 0);
            // C layout: col = c = cout, row = quad*4 + r = t within tile
            #pragma unroll
            for (int r = 0; r < 4; r++) {
                const int tt = tg + ti*16 + quad*4 + r;
                if (tt < NT) {
                    float v = acc[r];
                    v = (v >= 0.f) ? v : al2*v;
                    xo[(size_t)tt*CH] = f2bf(v);
                }
            }
        }
    }
}

// -------------------------------------------------------------------------
// GRU via MFMA — R10 single-wave structure + FC folded into the MFMA block
// (9th accumulator, fc_w broadcast across cols, k=16..47 = h region).
// Removes the hs8 ds_read, the 17-instr FC chain, and BOTH shfl_xor ds-ops
// with their serialized lgkmcnt waits.  +2 MFMAs, +3 masked sigmoids.
// -------------------------------------------------------------------------
__global__ __launch_bounds__(64) void gru_kernel(
    const unsigned short* __restrict__ xin,  // (NSEQ, NT, 16) bf16
    const float* __restrict__ h0,    // (NSEQ, 32)
    const float* __restrict__ w_ih,  // (96, 16)
    const float* __restrict__ w_hh,  // (96, 32)
    const float* __restrict__ b_ih, const float* __restrict__ b_hh,
    const float* __restrict__ fc_w, const float* __restrict__ fc_b,
    float* __restrict__ prob,        // (NSEQ, NT)
    float* __restrict__ hout)        // (NSEQ, 32)
{
    __shared__ unsigned short sv[16*72];     // [seq][x16|h32|pad16] bf16
    const int lane = threadIdx.x & 63;
    const int c    = lane & 15;
    const int quad = lane >> 4;
    const int base = blockIdx.x * 16;        // 481 blocks x 16 seq

    #define MKB(DST, G, CK)                                                    \
        { _Pragma("unroll") for (int j = 0; j < 8; j++) {                      \
            const int k = (CK)*32 + quad*8 + j;                                \
            const int g = (G);                                                 \
            float wv_;                                                         \
            if (g < 64)      wv_ = (k < 16) ? w_ih[g*16 + k]                   \
                                  : (k < 48) ? w_hh[g*32 + k - 16] : 0.f;      \
            else if (g < 96) wv_ = (k < 16) ? w_ih[g*16 + k] : 0.f;            \
            else             wv_ = (k >= 16 && k < 48)                         \
                                  ? w_hh[(g-32)*32 + k - 16] : 0.f;            \
            DST[j] = (short)f2bf(wv_); } }

    short8 B0a, B0b, B1a, B1b, B2a, B2b, B3a, B3b, B4a, B5a, B6a, B6b, B7a, B7b;
    MKB(B0a,       c, 0); MKB(B0b,       c, 1);   // r  units 0..15
    MKB(B1a,  16 + c, 0); MKB(B1b,  16 + c, 1);   // r  units 16..31
    MKB(B2a,  32 + c, 0); MKB(B2b,  32 + c, 1);   // z
    MKB(B3a,  48 + c, 0); MKB(B3b,  48 + c, 1);
    MKB(B4a,  64 + c, 0);                          // xn (chunk1 all-zero)
    MKB(B5a,  80 + c, 0);
    MKB(B6a,  96 + c, 0); MKB(B6b,  96 + c, 1);   // hn
    MKB(B7a, 112 + c, 0); MKB(B7b, 112 + c, 1);

    // FC fragment: same value in every col; k=16..47 <-> h units 0..31
    short8 Bfa, Bfb;
    { _Pragma("unroll") for (int j = 0; j < 8; j++) {
        const int k0 = quad*8 + j;
        Bfa[j] = (short)((k0 >= 16) ? f2bf(fc_w[k0 - 16]) : 0);
        const int k1 = 32 + quad*8 + j;
        Bfb[j] = (short)((k1 < 48) ? f2bf(fc_w[k1 - 16]) : 0);
    } }

    const float bi0 = b_ih[c]      + b_hh[c];
    const float bi1 = b_ih[16 + c] + b_hh[16 + c];
    const float bi2 = b_ih[32 + c] + b_hh[32 + c];
    const float bi3 = b_ih[48 + c] + b_hh[48 + c];
    const float bi4 = b_ih[64 + c];
    const float bi5 = b_ih[80 + c];
    const float bi6 = b_hh[64 + c];
    const float bi7 = b_hh[80 + c];
    const float fb = fc_b[0];

    // loop-invariant bias vectors fed straight into the first MFMA as C
    const f32x4 cb0 = {bi0, bi0, bi0, bi0};
    const f32x4 cb1 = {bi1, bi1, bi1, bi1};
    const f32x4 cb2 = {bi2, bi2, bi2, bi2};
    const f32x4 cb3 = {bi3, bi3, bi3, bi3};
    const f32x4 cb4 = {bi4, bi4, bi4, bi4};
    const f32x4 cb5 = {bi5, bi5, bi5, bi5};
    const f32x4 cb6 = {bi6, bi6, bi6, bi6};
    const f32x4 cb7 = {bi7, bi7, bi7, bi7};
    const f32x4 cb8 = {fb, fb, fb, fb};

    float hp00 = h0[(size_t)(base + quad*4 + 0)*HID + c];
    float hp01 = h0[(size_t)(base + quad*4 + 0)*HID + 16 + c];
    float hp10 = h0[(size_t)(base + quad*4 + 1)*HID + c];
    float hp11 = h0[(size_t)(base + quad*4 + 1)*HID + 16 + c];
    float hp20 = h0[(size_t)(base + quad*4 + 2)*HID + c];
    float hp21 = h0[(size_t)(base + quad*4 + 2)*HID + 16 + c];
    float hp30 = h0[(size_t)(base + quad*4 + 3)*HID + c];
    float hp31 = h0[(size_t)(base + quad*4 + 3)*HID + 16 + c];

    // ---- init LDS v-buffer ----
    *(uint2*)&sv[(lane >> 2)*72 + 48 + (lane & 3)*4] = make_uint2(0u, 0u);
    sv[(quad*4 + 0)*72 + 16 + c] = f2bf(hp00);  sv[(quad*4 + 0)*72 + 32 + c] = f2bf(hp01);
    sv[(quad*4 + 1)*72 + 16 + c] = f2bf(hp10);  sv[(quad*4 + 1)*72 + 32 + c] = f2bf(hp11);
    sv[(quad*4 + 2)*72 + 16 + c] = f2bf(hp20);  sv[(quad*4 + 2)*72 + 32 + c] = f2bf(hp21);
    sv[(quad*4 + 3)*72 + 16 + c] = f2bf(hp30);  sv[(quad*4 + 3)*72 + 32 + c] = f2bf(hp31);
    const unsigned short* xrow = xin + ((size_t)(base + (lane >> 2)))*NT*CH + (lane & 3)*4;
    {
        const uint2 x0v = *(const uint2*)(xrow);
        *(uint2*)&sv[(lane >> 2)*72 + (lane & 3)*4] = x0v;
    }
    uint2 nxA = *(const uint2*)(xrow + 1*CH);   // x(t=1)
    uint2 nxB = *(const uint2*)(xrow + 2*CH);   // x(t=2)
    __builtin_amdgcn_wave_barrier();

    #define GSTEP(R, HP0, HP1)                                                 \
        {                                                                      \
            const float rr0 = sig_(acc0[R]);                                   \
            const float rr1 = sig_(acc1[R]);                                   \
            const float zz0 = sig_(acc2[R]);                                   \
            const float zz1 = sig_(acc3[R]);                                   \
            const float aa0 = fmaf(rr0, acc6[R], acc4[R]);                     \
            const float aa1 = fmaf(rr1, acc7[R], acc5[R]);                     \
            const float nn0 = fmaf(2.f, sig_(2.f*aa0), -1.f);                  \
            const float nn1 = fmaf(2.f, sig_(2.f*aa1), -1.f);                  \
            HP0 = fmaf(zz0, HP0 - nn0, nn0);                                   \
            HP1 = fmaf(zz1, HP1 - nn1, nn1);                                   \
            unsigned hpk_;                                                     \
            asm("v_cvt_pk_bf16_f32 %0, %1, %2"                                 \
                : "=v"(hpk_) : "v"(HP0), "v"(HP1));                            \
            sv[(quad*4 + (R))*72 + 16 + c] = (unsigned short)hpk_;             \
            sv[(quad*4 + (R))*72 + 32 + c] = (unsigned short)(hpk_ >> 16);     \
        }

    for (int t = 0; t < NT; t++) {
        const short8 a0  = *(const short8*)&sv[c*72 + quad*8];        // k 0..31
        const short8 a1  = *(const short8*)&sv[c*72 + 32 + quad*8];   // k 32..63
        __builtin_amdgcn_wave_barrier();   // pin reads before this iter's writes

        // prefetch x(t+3)
        const int tn = (t + 3 < NT) ? t + 3 : NT - 1;
        const uint2 fx = *(const uint2*)(xrow + (size_t)tn*CH);

        f32x4 acc0 = __builtin_amdgcn_mfma_f32_16x16x32_bf16(a0, B0a, cb0, 0, 0, 0);
        f32x4 acc1 = __builtin_amdgcn_mfma_f32_16x16x32_bf16(a0, B1a, cb1, 0, 0, 0);
        f32x4 acc2 = __builtin_amdgcn_mfma_f32_16x16x32_bf16(a0, B2a, cb2, 0, 0, 0);
        f32x4 acc3 = __builtin_amdgcn_mfma_f32_16x16x32_bf16(a0, B3a, cb3, 0, 0, 0);
        f32x4 acc4 = __builtin_amdgcn_mfma_f32_16x16x32_bf16(a0, B4a, cb4, 0, 0, 0);
        f32x4 acc5 = __builtin_amdgcn_mfma_f32_16x16x32_bf16(a0, B5a, cb5, 0, 0, 0);
        f32x4 acc6 = __builtin_amdgcn_mfma_f32_16x16x32_bf16(a0, B6a, cb6, 0, 0, 0);
        f32x4 acc7 = __builtin_amdgcn_mfma_f32_16x16x32_bf16(a0, B7a, cb7, 0, 0, 0);
        f32x4 acc8 = __builtin_amdgcn_mfma_f32_16x16x32_bf16(a0, Bfa, cb8, 0, 0, 0);
        acc0 = __builtin_amdgcn_mfma_f32_16x16x32_bf16(a1, B0b, acc0, 0, 0, 0);
        acc1 = __builtin_amdgcn_mfma_f32_16x16x32_bf16(a1, B1b, acc1, 0, 0, 0);
        acc2 = __builtin_amdgcn_mfma_f32_16x16x32_bf16(a1, B2b, acc2, 0, 0, 0);
        acc3 = __builtin_amdgcn_mfma_f32_16x16x32_bf16(a1, B3b, acc3, 0, 0, 0);
        acc6 = __builtin_amdgcn_mfma_f32_16x16x32_bf16(a1, B6b, acc6, 0, 0, 0);
        acc7 = __builtin_amdgcn_mfma_f32_16x16x32_bf16(a1, B7b, acc7, 0, 0, 0);
        acc8 = __builtin_amdgcn_mfma_f32_16x16x32_bf16(a1, Bfb, acc8, 0, 0, 0);

        // prob[t-1]: acc8[R] = logit for seq quad*4+R (same in every col)
        if (t > 0 && c == 0) {
            prob[(size_t)(base + quad*4 + 0)*NT + (t - 1)] = sig_(acc8[0]);
            prob[(size_t)(base + quad*4 + 1)*NT + (t - 1)] = sig_(acc8[1]);
            prob[(size_t)(base + quad*4 + 2)*NT + (t - 1)] = sig_(acc8[2]);
            prob[(size_t)(base + quad*4 + 3)*NT + (t - 1)] = sig_(acc8[3]);
        }

        GSTEP(0, hp00, hp01);
        GSTEP(1, hp10, hp11);
        GSTEP(2, hp20, hp21);
        GSTEP(3, hp30, hp31);

        // stage x(t+1), rotate prefetch pipeline
        *(uint2*)&sv[(lane >> 2)*72 + (lane & 3)*4] = nxA;
        nxA = nxB; nxB = fx;
        __builtin_amdgcn_wave_barrier();
    }

    // prob for the final step (h_NT is in sv)
    {
        const short8 a0  = *(const short8*)&sv[c*72 + quad*8];
        const short8 a1  = *(const short8*)&sv[c*72 + 32 + quad*8];
        f32x4 acc8 = __builtin_amdgcn_mfma_f32_16x16x32_bf16(a0, Bfa, cb8, 0, 0, 0);
        acc8 = __builtin_amdgcn_mfma_f32_16x16x32_bf16(a1, Bfb, acc8, 0, 0, 0);
        if (c == 0) {
            prob[(size_t)(base + quad*4 + 0)*NT + (NT - 1)] = sig_(acc8[0]);
            prob[(size_t)(base + quad*4 + 1)*NT + (NT - 1)] = sig_(acc8[1]);
            prob[(size_t)(base + quad*4 + 2)*NT + (NT - 1)] = sig_(acc8[2]);
            prob[(size_t)(base + quad*4 + 3)*NT + (NT - 1)] = sig_(acc8[3]);
        }
    }

    hout[(size_t)(base + quad*4 + 0)*HID + c]      = hp00;
    hout[(size_t)(base + quad*4 + 0)*HID + 16 + c] = hp01;
    hout[(size_t)(base + quad*4 + 1)*HID + c]      = hp10;
    hout[(size_t)(base + quad*4 + 1)*HID + 16 + c] = hp11;
    hout[(size_t)(base + quad*4 + 2)*HID + c]      = hp20;
    hout[(size_t)(base + quad*4 + 2)*HID + 16 + c] = hp21;
    hout[(size_t)(base + quad*4 + 3)*HID + c]      = hp30;
    hout[(size_t)(base + quad*4 + 3)*HID + 16 + c] = hp31;
}

// -------------------------------------------------------------------------
extern "C" void kernel_launch(void* const* d_in, const int* in_sizes, int n_in,
                              void* d_out, int out_size, void* d_ws, size_t ws_size,
                              hipStream_t stream)
{
    const float* feat = (const float*)d_in[0];
    const float* h0   = (const float*)d_in[1];
    const float* w1   = (const float*)d_in[2];
    const float* b1   = (const float*)d_in[3];
    const float* a1   = (const float*)d_in[4];
    const float* w2   = (const float*)d_in[5];
    const float* b2   = (const float*)d_in[6];
    const float* a2   = (const float*)d_in[7];
    const float* wih  = (const float*)d_in[8];
    const float* whh  = (const float*)d_in[9];
    const float* bih  = (const float*)d_in[10];
    const float* bhh  = (const float*)d_in[11];
    const float* fcw  = (const float*)d_in[12];
    const float* fcb  = (const float*)d_in[13];

    unsigned short* xbuf = (unsigned short*)d_ws;            // 123.1 MB bf16
    unsigned short* y1   = xbuf + (size_t)NSEQ*NT*CH;        // 123.1 MB bf16 (b,f,t,ch)
    float* prob = (float*)d_out;                             // (B, F, T)
    float* hout = prob + (size_t)NSEQ*NT;                    // (1, NSEQ, 32)

    dim3 c1grid(NB, 121, 2);                                 // 4 f-waves/block
    conv1_kernel<<<c1grid, 256, 0, stream>>>(feat, w1, b1, a1, y1);
    dim3 c2grid(NB, 121, 4);                                 // 4 f x 128 t per block
    conv2_kernel<<<c2grid, 256, 0, stream>>>(y1, w2, b2, a2, xbuf);
    gru_kernel<<<NSEQ/16, 64, 0, stream>>>(xbuf, h0, wih, whh, bih, bhh, fcw, fcb, prob, hout);
}